// Round 7
// baseline (2754.188 us; speedup 1.0000x reference)
//
#include <hip/hip_runtime.h>
#include <math.h>

#define TT  1024
#define DD  2048
#define NHH 2048
#define CC  1000

#define LDS_LOAD_ACQ(P)  __hip_atomic_load((P), __ATOMIC_ACQUIRE, __HIP_MEMORY_SCOPE_WORKGROUP)
#define LDS_ADD_REL(P)   __hip_atomic_fetch_add((P), 1, __ATOMIC_RELEASE, __HIP_MEMORY_SCOPE_WORKGROUP)

// ---------------------------------------------------------------------------
// k_init: poison all 4 exchange slots' tags EVERY launch. CRITICAL for graph
// replays: leftover tags 1021..1024 from the previous replay exactly match
// expected tags at t=1021..1023 of the next run (R3's divergence).
// ---------------------------------------------------------------------------
__global__ void k_init(unsigned long long* __restrict__ Hbuf) {
    int i = blockIdx.x * blockDim.x + threadIdx.x;
    if (i < 4 * NHH) Hbuf[i] = 0xFFFFFFFF00000000ull;
}

// ---------------------------------------------------------------------------
// GEMM: XH = x @ Wh^T ; XZ = x @ Wz^T + bz   (fp32, 64x64 tile, BK=32)
// ---------------------------------------------------------------------------
__global__ __launch_bounds__(256) void k_gemm(const float* __restrict__ X,
                                              const float* __restrict__ Wh,
                                              const float* __restrict__ Wz,
                                              const float* __restrict__ bz,
                                              float* __restrict__ XH,
                                              float* __restrict__ XZ) {
    __shared__ float As[32][68];   // [k][m]
    __shared__ float Bs[32][68];   // [k][n]
    const int z = blockIdx.z;
    const float* __restrict__ W = z ? Wz : Wh;
    float* __restrict__ OUT = z ? XZ : XH;
    const int n0 = blockIdx.x * 64;
    const int m0 = blockIdx.y * 64;
    const int tid = threadIdx.x;
    const int tx = tid & 15, ty = tid >> 4;
    const int lr = tid >> 2;           // 0..63 row within tile
    const int lc = (tid & 3) * 8;      // 0,8,16,24 col base

    float acc[4][4] = {};
    for (int k0 = 0; k0 < DD; k0 += 32) {
        float4 a0 = *(const float4*)&X[(size_t)(m0 + lr) * DD + k0 + lc];
        float4 a1 = *(const float4*)&X[(size_t)(m0 + lr) * DD + k0 + lc + 4];
        float4 b0 = *(const float4*)&W[(size_t)(n0 + lr) * DD + k0 + lc];
        float4 b1 = *(const float4*)&W[(size_t)(n0 + lr) * DD + k0 + lc + 4];
        As[lc+0][lr]=a0.x; As[lc+1][lr]=a0.y; As[lc+2][lr]=a0.z; As[lc+3][lr]=a0.w;
        As[lc+4][lr]=a1.x; As[lc+5][lr]=a1.y; As[lc+6][lr]=a1.z; As[lc+7][lr]=a1.w;
        Bs[lc+0][lr]=b0.x; Bs[lc+1][lr]=b0.y; Bs[lc+2][lr]=b0.z; Bs[lc+3][lr]=b0.w;
        Bs[lc+4][lr]=b1.x; Bs[lc+5][lr]=b1.y; Bs[lc+6][lr]=b1.z; Bs[lc+7][lr]=b1.w;
        __syncthreads();
#pragma unroll
        for (int kk = 0; kk < 32; ++kk) {
            float4 av = *(const float4*)&As[kk][ty * 4];
            float4 bv = *(const float4*)&Bs[kk][tx * 4];
            acc[0][0] = fmaf(av.x, bv.x, acc[0][0]); acc[0][1] = fmaf(av.x, bv.y, acc[0][1]);
            acc[0][2] = fmaf(av.x, bv.z, acc[0][2]); acc[0][3] = fmaf(av.x, bv.w, acc[0][3]);
            acc[1][0] = fmaf(av.y, bv.x, acc[1][0]); acc[1][1] = fmaf(av.y, bv.y, acc[1][1]);
            acc[1][2] = fmaf(av.y, bv.z, acc[1][2]); acc[1][3] = fmaf(av.y, bv.w, acc[1][3]);
            acc[2][0] = fmaf(av.z, bv.x, acc[2][0]); acc[2][1] = fmaf(av.z, bv.y, acc[2][1]);
            acc[2][2] = fmaf(av.z, bv.z, acc[2][2]); acc[2][3] = fmaf(av.z, bv.w, acc[2][3]);
            acc[3][0] = fmaf(av.w, bv.x, acc[3][0]); acc[3][1] = fmaf(av.w, bv.y, acc[3][1]);
            acc[3][2] = fmaf(av.w, bv.z, acc[3][2]); acc[3][3] = fmaf(av.w, bv.w, acc[3][3]);
        }
        __syncthreads();
    }
    float4 bias = make_float4(0.f, 0.f, 0.f, 0.f);
    if (z) bias = *(const float4*)&bz[n0 + tx * 4];
#pragma unroll
    for (int i = 0; i < 4; ++i) {
        float4 o = make_float4(acc[i][0] + bias.x, acc[i][1] + bias.y,
                               acc[i][2] + bias.z, acc[i][3] + bias.w);
        *(float4*)&OUT[(size_t)(m0 + ty * 4 + i) * NHH + n0 + tx * 4] = o;
    }
}

// ---------------------------------------------------------------------------
// Recurrent scan v5: U in REGISTERS, wave-local gates.
// Evidence R2/R4/R5/R6: step time pinned at 1.7-2.0 us whenever U streams
// through a ~100 B/cy pipe (L2 / scratch / LDS: 160 KB/step / 85 B/cy
// ~= 1900 cy on the publish critical path). Fix: 512 thr, 8 waves, wave w
// owns output element j = 8*blk + w and holds Uz[j],Uh[j] as 16 named
// float4s = 64 VGPRs/lane (vs 128 that R2/R4 failed to keep). Both dots for
// j reduce within the wave -> gates + publish wave-local, no dot_s.
// Sync: ONE LDS counter. fill(s) follows matvec(s) in-wave, so passing
// fill_cnt >= 8(t-1) proves all local waves finished matvec(t-1), which is
// the WAR guard for overwriting Hs[t&1] (= Hs[(t-2)&1]).
// Exchange: 4-slot tagged (epoch<<32|f32bits) Hbuf, relaxed agent-scope u64
// atomics, k_init-poisoned every launch (R1-R6 proven).
// Per-step chain target: matvec ~300cy + reduce ~200cy + gates ~100cy,
// exchange RTT mostly hidden by early pv issue.
// ---------------------------------------------------------------------------
__global__ __launch_bounds__(512) void k_recur(
    const float* __restrict__ XH, const float* __restrict__ XZ,
    const float* __restrict__ Uh, const float* __restrict__ Uz,
    const float* __restrict__ zt0, const float* __restrict__ ht0,
    const float* __restrict__ hp0,
    unsigned long long* __restrict__ Hbuf) {
    __shared__ float Hs[2][NHH];      // 16 KB, parity by t
    __shared__ int fill_cnt;
    const int tid  = threadIdx.x;
    const int wave = tid >> 6, lane = tid & 63;
    const int base8 = blockIdx.x * 8;
    const int j = base8 + wave;        // output element owned by this wave

    // this wave's two U rows -> 16 named float4s (64 VGPR/lane)
    const float* __restrict__ rz = Uz + (size_t)j * NHH + lane * 4;
    const float* __restrict__ rh = Uh + (size_t)j * NHH + lane * 4;
    float4 uz0 = *(const float4*)&rz[0 * 256];
    float4 uz1 = *(const float4*)&rz[1 * 256];
    float4 uz2 = *(const float4*)&rz[2 * 256];
    float4 uz3 = *(const float4*)&rz[3 * 256];
    float4 uz4 = *(const float4*)&rz[4 * 256];
    float4 uz5 = *(const float4*)&rz[5 * 256];
    float4 uz6 = *(const float4*)&rz[6 * 256];
    float4 uz7 = *(const float4*)&rz[7 * 256];
    float4 uh0 = *(const float4*)&rh[0 * 256];
    float4 uh1 = *(const float4*)&rh[1 * 256];
    float4 uh2 = *(const float4*)&rh[2 * 256];
    float4 uh3 = *(const float4*)&rh[3 * 256];
    float4 uh4 = *(const float4*)&rh[4 * 256];
    float4 uh5 = *(const float4*)&rh[5 * 256];
    float4 uh6 = *(const float4*)&rh[6 * 256];
    float4 uh7 = *(const float4*)&rh[7 * 256];

    if (tid == 0) fill_cnt = 0;
    // Hs[0] = P_0 = hprev0
    *(float4*)&Hs[0][tid * 4] = *(const float4*)&hp0[tid * 4];

    // own P_1 from initial gates; publish epoch 1; preload x-proj row 0
    float p = 0.f, xz_cur = 0.f, xh_cur = 0.f;
    if (lane == 0) {
        float z0 = zt0[j], g0 = ht0[j], p0 = hp0[j];
        p = (1.0f - z0) * p0 + z0 * g0;
        unsigned long long pr = (1ull << 32) | (unsigned long long)__float_as_uint(p);
        __hip_atomic_store(&Hbuf[(size_t)1 * NHH + j], pr,
                           __ATOMIC_RELAXED, __HIP_MEMORY_SCOPE_AGENT);
        xz_cur = XZ[j];
        xh_cur = XH[j];
    }
    __syncthreads();   // the ONLY barrier

#define MVSTEP(C) { \
        float4 h4 = *(const float4*)&HA[(C) * 256 + lane * 4]; \
        az = fmaf(uz##C.x, h4.x, fmaf(uz##C.y, h4.y, fmaf(uz##C.z, h4.z, fmaf(uz##C.w, h4.w, az)))); \
        ah = fmaf(uh##C.x, h4.x, fmaf(uh##C.y, h4.y, fmaf(uh##C.z, h4.z, fmaf(uh##C.w, h4.w, ah)))); }

    for (int t = 1; t < TT; ++t) {
        // (i) issue epoch-t tag loads early (4/thread, coalesced); validated late
        const unsigned long long* __restrict__ src = Hbuf + (size_t)(t & 3) * NHH;
        unsigned long long pv0 = __hip_atomic_load(&src[0 * 512 + tid], __ATOMIC_RELAXED, __HIP_MEMORY_SCOPE_AGENT);
        unsigned long long pv1 = __hip_atomic_load(&src[1 * 512 + tid], __ATOMIC_RELAXED, __HIP_MEMORY_SCOPE_AGENT);
        unsigned long long pv2 = __hip_atomic_load(&src[2 * 512 + tid], __ATOMIC_RELAXED, __HIP_MEMORY_SCOPE_AGENT);
        unsigned long long pv3 = __hip_atomic_load(&src[3 * 512 + tid], __ATOMIC_RELAXED, __HIP_MEMORY_SCOPE_AGENT);
        // (ii) wait for P_{t-1} in Hs[(t-1)&1] (t=1: prologue-filled)
        if (t > 1)
            while (LDS_LOAD_ACQ(&fill_cnt) < 8 * (t - 1)) __builtin_amdgcn_s_sleep(0);
        // (iii) matvec on P_{t-1}: U in registers, H from LDS
        const float* __restrict__ HA = Hs[(t - 1) & 1];
        float az = 0.f, ah = 0.f;
        MVSTEP(0) MVSTEP(1) MVSTEP(2) MVSTEP(3)
        MVSTEP(4) MVSTEP(5) MVSTEP(6) MVSTEP(7)
        // (iv) wave-wide reduce of both dots
#pragma unroll
        for (int off = 1; off <= 32; off <<= 1) {
            az += __shfl_xor(az, off);
            ah += __shfl_xor(ah, off);
        }
        // (v) gates + publish, wave-local (lane 0)
        if (lane == 0) {
            float z = 1.0f / (1.0f + expf(-(xz_cur + az)));
            float g = tanhf(xh_cur + ah);
            p = (1.0f - z) * p + z * g;   // P_{t+1}
            unsigned long long pr = ((unsigned long long)(unsigned)(t + 1) << 32)
                                  | (unsigned long long)__float_as_uint(p);
            __hip_atomic_store(&Hbuf[(size_t)((t + 1) & 3) * NHH + j], pr,
                               __ATOMIC_RELAXED, __HIP_MEMORY_SCOPE_AGENT);
            // prefetch x-proj row t (consumed at iteration t+1)
            xz_cur = XZ[(size_t)t * NHH + j];
            xh_cur = XH[(size_t)t * NHH + j];
        }
        // (vi) validate epoch-t tags (batched parallel retry)
        for (;;) {
            unsigned stale = 0;
            if ((unsigned)(pv0 >> 32) != (unsigned)t) stale |= 1u;
            if ((unsigned)(pv1 >> 32) != (unsigned)t) stale |= 2u;
            if ((unsigned)(pv2 >> 32) != (unsigned)t) stale |= 4u;
            if ((unsigned)(pv3 >> 32) != (unsigned)t) stale |= 8u;
            if (!stale) break;
            __builtin_amdgcn_s_sleep(1);
            if (stale & 1u) pv0 = __hip_atomic_load(&src[0 * 512 + tid], __ATOMIC_RELAXED, __HIP_MEMORY_SCOPE_AGENT);
            if (stale & 2u) pv1 = __hip_atomic_load(&src[1 * 512 + tid], __ATOMIC_RELAXED, __HIP_MEMORY_SCOPE_AGENT);
            if (stale & 4u) pv2 = __hip_atomic_load(&src[2 * 512 + tid], __ATOMIC_RELAXED, __HIP_MEMORY_SCOPE_AGENT);
            if (stale & 8u) pv3 = __hip_atomic_load(&src[3 * 512 + tid], __ATOMIC_RELAXED, __HIP_MEMORY_SCOPE_AGENT);
        }
        // (vii) fill Hs[t&1] = P_t; signal (fill follows matvec in-wave)
        float* __restrict__ HB = Hs[t & 1];
        HB[0 * 512 + tid] = __uint_as_float((unsigned)pv0);
        HB[1 * 512 + tid] = __uint_as_float((unsigned)pv1);
        HB[2 * 512 + tid] = __uint_as_float((unsigned)pv2);
        HB[3 * 512 + tid] = __uint_as_float((unsigned)pv3);
        if (lane == 63) LDS_ADD_REL(&fill_cnt);
    }
#undef MVSTEP
}

// ---------------------------------------------------------------------------
// logits[r] = Wout[r,:] . P_1024   (epoch 1024 -> slot 0, value in low bits)
// ---------------------------------------------------------------------------
__global__ __launch_bounds__(256) void k_logits(const unsigned long long* __restrict__ Hbuf,
                                                const float* __restrict__ Wout,
                                                float* __restrict__ lg) {
    __shared__ float Hs[NHH];
    const int tid = threadIdx.x;
    for (int k = tid; k < NHH; k += 256) Hs[k] = __uint_as_float((unsigned)Hbuf[k]);
    __syncthreads();
    const int wave = tid >> 6, lane = tid & 63;
    const int row = blockIdx.x * 4 + wave;
    float a = 0.f;
#pragma unroll
    for (int c = 0; c < 8; ++c) {
        float4 w = *(const float4*)&Wout[(size_t)row * NHH + c * 256 + lane * 4];
        float4 h = *(const float4*)&Hs[c * 256 + lane * 4];
        a = fmaf(w.x, h.x, fmaf(w.y, h.y, fmaf(w.z, h.z, fmaf(w.w, h.w, a))));
    }
#pragma unroll
    for (int off = 32; off > 0; off >>= 1) a += __shfl_xor(a, off);
    if (lane == 0) lg[row] = a;
}

// ---------------------------------------------------------------------------
// softmax over 1000 logits, single block
// ---------------------------------------------------------------------------
__global__ __launch_bounds__(1024) void k_softmax(const float* __restrict__ lg,
                                                  float* __restrict__ out) {
    const int i = threadIdx.x;
    __shared__ float red[16];
    __shared__ float bc[2];
    float v = (i < CC) ? lg[i] : -3.0e38f;
    float m = v;
#pragma unroll
    for (int off = 32; off > 0; off >>= 1) m = fmaxf(m, __shfl_xor(m, off));
    if ((i & 63) == 0) red[i >> 6] = m;
    __syncthreads();
    if (i == 0) { float mm = red[0]; for (int k = 1; k < 16; ++k) mm = fmaxf(mm, red[k]); bc[0] = mm; }
    __syncthreads();
    float e = (i < CC) ? expf(v - bc[0]) : 0.f;
    float s = e;
#pragma unroll
    for (int off = 32; off > 0; off >>= 1) s += __shfl_xor(s, off);
    if ((i & 63) == 0) red[i >> 6] = s;
    __syncthreads();
    if (i == 0) { float ss = 0.f; for (int k = 0; k < 16; ++k) ss += red[k]; bc[1] = ss; }
    __syncthreads();
    if (i < CC) out[i] = e / bc[1];
}

extern "C" void kernel_launch(void* const* d_in, const int* in_sizes, int n_in,
                              void* d_out, int out_size, void* d_ws, size_t ws_size,
                              hipStream_t stream) {
    const float* x    = (const float*)d_in[0];
    const float* Wh   = (const float*)d_in[1];
    const float* Wz   = (const float*)d_in[2];
    // d_in[3] = Wr  (dead code in reference)
    const float* Uh   = (const float*)d_in[4];
    const float* Uz   = (const float*)d_in[5];
    const float* bz   = (const float*)d_in[6];
    // d_in[7] = Ur, d_in[8] = br (dead code)
    const float* Wout = (const float*)d_in[9];
    // d_in[10] = h0 (overwritten before first use since T>=1)
    const float* zt0  = (const float*)d_in[11];
    const float* ht0  = (const float*)d_in[12];
    const float* hp0  = (const float*)d_in[13];
    float* out = (float*)d_out;

    float* XH = (float*)d_ws;                                   // T*NH f32
    float* XZ = XH + (size_t)TT * NHH;                          // T*NH f32
    unsigned long long* Hbuf = (unsigned long long*)(XZ + (size_t)TT * NHH); // 4*NH u64
    float* lg = (float*)(Hbuf + 4 * NHH);                       // CC f32

    k_init<<<dim3((4 * NHH + 255) / 256), dim3(256), 0, stream>>>(Hbuf);
    k_gemm<<<dim3(NHH / 64, TT / 64, 2), dim3(256), 0, stream>>>(x, Wh, Wz, bz, XH, XZ);
    k_recur<<<dim3(256), dim3(512), 0, stream>>>(XH, XZ, Uh, Uz, zt0, ht0, hp0, Hbuf);
    k_logits<<<dim3(250), dim3(256), 0, stream>>>(Hbuf, Wout, lg);
    k_softmax<<<dim3(1), dim3(1024), 0, stream>>>(lg, out);
}